// Round 4
// baseline (250.195 us; speedup 1.0000x reference)
//
#include <hip/hip_runtime.h>
#include <hip/hip_bf16.h>
#include <hip/hip_cooperative_groups.h>

namespace cg = cooperative_groups;

// B=2, S=2048, D=512, K_routes=64, H=8 (heads irrelevant: k-weighted sum is head-uniform)
#define S_DIM 2048
#define D_DIM 512
#define B_DIM 2
#define K_RT  64
#define M_DIM 4096   // B*S

typedef __attribute__((ext_vector_type(8))) short short8;   // 8 bf16 = 4 VGPRs (MFMA A/B frag)
typedef __attribute__((ext_vector_type(4))) float f32x4;    // MFMA C/D frag

static __device__ __forceinline__ float bf16lo_to_f(unsigned u) {
    union { unsigned u; float f; } c; c.u = u << 16; return c.f;
}
static __device__ __forceinline__ float bf16hi_to_f(unsigned u) {
    union { unsigned u; float f; } c; c.u = u & 0xffff0000u; return c.f;
}
static __device__ __forceinline__ unsigned short f_to_bf16(float f) {
    union { float f; unsigned u; } c; c.f = f;
    unsigned u = c.u;
    u += 0x7fffu + ((u >> 16) & 1u);   // RTNE (inputs finite/normal)
    return (unsigned short)(u >> 16);
}
static __device__ __forceinline__ unsigned pk2(float a, float b) {
    return (unsigned)f_to_bf16(a) | ((unsigned)f_to_bf16(b) << 16);
}

// 64x64 block tile, 4 waves each 32x32 (2x2 frags of 16x16x32), BK=32.
#define GBM 64
#define GBN 64
#define GBK 32
#define LROW 40   // padded LDS row (bf16): 80 B stride, 16B-aligned, 2-way alias max (free)

struct SMem {
    unsigned short As[GBM * LROW];
    unsigned short Bs[GBN * LROW];
};

// C = A * B^T. A: 4096x512 (fp32 if AF32 else bf16), B: W 512x512 fp32 (inline cast).
// OUTF32: C fp32 = acc + bias[n] + residual[m,n]; else C bf16.
template<bool AF32, bool OUTF32>
static __device__ __forceinline__ void gemm_tile(
    const void* __restrict__ Av, const float* __restrict__ Bw,
    void* __restrict__ Cv, const float* __restrict__ bias,
    const float* __restrict__ residual, SMem& sm, int m0, int n0)
{
    const int tid  = threadIdx.x;
    const int lane = tid & 63;
    const int wv   = tid >> 6;
    const int wm   = (wv & 1) * 32;
    const int wn   = (wv >> 1) * 32;

    const int lr = tid >> 2;            // staging row 0..63
    const int lc = (tid & 3) * 8;       // staging k offset 0,8,16,24

    const int mi = lane & 15;
    const int kg = lane >> 4;

    f32x4 acc[2][2] = {};

    for (int k0 = 0; k0 < D_DIM; k0 += GBK) {
        uint4 apk, bpk;
        if (AF32) {
            const float* A = (const float*)Av;
            const float4 a0 = *(const float4*)(A + (size_t)(m0 + lr) * D_DIM + k0 + lc);
            const float4 a1 = *(const float4*)(A + (size_t)(m0 + lr) * D_DIM + k0 + lc + 4);
            apk.x = pk2(a0.x, a0.y); apk.y = pk2(a0.z, a0.w);
            apk.z = pk2(a1.x, a1.y); apk.w = pk2(a1.z, a1.w);
        } else {
            const unsigned short* A = (const unsigned short*)Av;
            apk = *(const uint4*)(A + (size_t)(m0 + lr) * D_DIM + k0 + lc);
        }
        {
            const float4 b0 = *(const float4*)(Bw + (size_t)(n0 + lr) * D_DIM + k0 + lc);
            const float4 b1 = *(const float4*)(Bw + (size_t)(n0 + lr) * D_DIM + k0 + lc + 4);
            bpk.x = pk2(b0.x, b0.y); bpk.y = pk2(b0.z, b0.w);
            bpk.z = pk2(b1.x, b1.y); bpk.w = pk2(b1.z, b1.w);
        }
        *(uint4*)(sm.As + lr * LROW + lc) = apk;
        *(uint4*)(sm.Bs + lr * LROW + lc) = bpk;
        __syncthreads();

        short8 af0 = *(const short8*)(sm.As + (wm +      mi) * LROW + kg * 8);
        short8 af1 = *(const short8*)(sm.As + (wm + 16 + mi) * LROW + kg * 8);
        short8 bf0 = *(const short8*)(sm.Bs + (wn +      mi) * LROW + kg * 8);
        short8 bf1 = *(const short8*)(sm.Bs + (wn + 16 + mi) * LROW + kg * 8);

        acc[0][0] = __builtin_amdgcn_mfma_f32_16x16x32_bf16(af0, bf0, acc[0][0], 0, 0, 0);
        acc[0][1] = __builtin_amdgcn_mfma_f32_16x16x32_bf16(af0, bf1, acc[0][1], 0, 0, 0);
        acc[1][0] = __builtin_amdgcn_mfma_f32_16x16x32_bf16(af1, bf0, acc[1][0], 0, 0, 0);
        acc[1][1] = __builtin_amdgcn_mfma_f32_16x16x32_bf16(af1, bf1, acc[1][1], 0, 0, 0);
        __syncthreads();
    }

    // C/D layout: col = lane&15, row = (lane>>4)*4 + reg   [verified m89/m91]
    const int rb  = (lane >> 4) * 4;
    const int col = lane & 15;
    #pragma unroll
    for (int i = 0; i < 2; ++i) {
        #pragma unroll
        for (int j = 0; j < 2; ++j) {
            #pragma unroll
            for (int r = 0; r < 4; ++r) {
                const int m = m0 + wm + i * 16 + rb + r;
                const int n = n0 + wn + j * 16 + col;
                const float v = acc[i][j][r];
                if (OUTF32) {
                    ((float*)Cv)[(size_t)m * D_DIM + n] = v + bias[n] + residual[(size_t)m * D_DIM + n];
                } else {
                    ((unsigned short*)Cv)[(size_t)m * D_DIM + n] = f_to_bf16(v);
                }
            }
        }
    }
}

// fused[b,s,:] = sum_k softmax_k(-dist[s,routes[s,k]]) * h[b,routes[s,k],:]
// One wave per (b,s): lane k owns route_k/w_k (in-register softmax); k-loop
// broadcasts via __shfl, 64 lanes read one 1 KB bf16 row coalesced (16 B/lane).
static __device__ __forceinline__ void fuse_unit(
    const unsigned short* __restrict__ h, const int* __restrict__ routes,
    const float* __restrict__ distances, unsigned short* __restrict__ fused,
    int b, int s, int lane)
{
    const int rt = routes[s * K_RT + lane];
    const float v = -distances[(size_t)s * S_DIM + rt];
    float mx = v;
    #pragma unroll
    for (int off = 32; off >= 1; off >>= 1) mx = fmaxf(mx, __shfl_xor(mx, off, 64));
    const float e = __expf(v - mx);
    float sum = e;
    #pragma unroll
    for (int off = 32; off >= 1; off >>= 1) sum += __shfl_xor(sum, off, 64);
    const float wl = e / sum;

    const unsigned short* hb = h + (size_t)b * S_DIM * D_DIM;
    float acc[8] = {};
    #pragma unroll 4
    for (int k = 0; k < 64; ++k) {
        const int   rk = __shfl(rt, k, 64);
        const float wk = __shfl(wl, k, 64);
        const uint4 p = *(const uint4*)(hb + (size_t)rk * D_DIM + lane * 8);
        acc[0] = fmaf(wk, bf16lo_to_f(p.x), acc[0]);
        acc[1] = fmaf(wk, bf16hi_to_f(p.x), acc[1]);
        acc[2] = fmaf(wk, bf16lo_to_f(p.y), acc[2]);
        acc[3] = fmaf(wk, bf16hi_to_f(p.y), acc[3]);
        acc[4] = fmaf(wk, bf16lo_to_f(p.z), acc[4]);
        acc[5] = fmaf(wk, bf16hi_to_f(p.z), acc[5]);
        acc[6] = fmaf(wk, bf16lo_to_f(p.w), acc[6]);
        acc[7] = fmaf(wk, bf16hi_to_f(p.w), acc[7]);
    }
    uint4 o;
    o.x = pk2(acc[0], acc[1]);
    o.y = pk2(acc[2], acc[3]);
    o.z = pk2(acc[4], acc[5]);
    o.w = pk2(acc[6], acc[7]);
    *(uint4*)(fused + ((size_t)b * S_DIM + s) * D_DIM + lane * 8) = o;
}

// One cooperative kernel: gemm1 -> grid.sync -> fuse -> grid.sync -> gemm2.
// 512 blocks x 256 threads = 2 blocks/CU (co-resident), one 64x64 tile per block per gemm.
__global__ __launch_bounds__(256, 2) void mega(
    const float* __restrict__ x, const int* __restrict__ routes,
    const float* __restrict__ distances, const float* __restrict__ W_in,
    const float* __restrict__ W_out, const float* __restrict__ b_out,
    float* __restrict__ out, unsigned short* __restrict__ hb,
    unsigned short* __restrict__ fb)
{
    __shared__ SMem sm;
    const int bx = blockIdx.x;
    const int m0 = (bx >> 3) * GBM;
    const int n0 = (bx & 7) * GBN;

    // phase 1: h = x @ W_in^T  (bf16 out)
    gemm_tile<true, false>(x, W_in, hb, nullptr, nullptr, sm, m0, n0);
    cg::this_grid().sync();

    // phase 2: softmax + gather + weighted sum; 8 (b,s) units per block
    {
        const int lane = threadIdx.x & 63;
        const int wv   = threadIdx.x >> 6;
        #pragma unroll
        for (int i = 0; i < 2; ++i) {
            const int unit = bx * 8 + wv * 2 + i;    // 0..4095
            fuse_unit(hb, routes, distances, fb, unit >> 11, unit & (S_DIM - 1), lane);
        }
    }
    cg::this_grid().sync();

    // phase 3: out = fused @ W_out^T + b_out + x  (fp32 out)
    gemm_tile<false, true>(fb, W_out, out, b_out, x, sm, m0, n0);
}

// ---------------------------------------------------------------------------
extern "C" void kernel_launch(void* const* d_in, const int* in_sizes, int n_in,
                              void* d_out, int out_size, void* d_ws, size_t ws_size,
                              hipStream_t stream) {
    const float* x         = (const float*)d_in[0];
    const int*   routes    = (const int*)  d_in[1];
    const float* distances = (const float*)d_in[2];
    const float* W_in      = (const float*)d_in[3];
    const float* W_out     = (const float*)d_in[4];
    const float* b_out     = (const float*)d_in[5];
    float* out = (float*)d_out;

    // ws layout (bf16 elems): h 2M | fused 2M  = 8 MB
    unsigned short* hb = (unsigned short*)d_ws;
    unsigned short* fb = hb + (size_t)M_DIM * D_DIM;

    void* args[] = {
        (void*)&x, (void*)&routes, (void*)&distances, (void*)&W_in,
        (void*)&W_out, (void*)&b_out, (void*)&out, (void*)&hb, (void*)&fb
    };
    hipLaunchCooperativeKernel((const void*)mega, dim3(512), dim3(256), args, 0, stream);
}

// Round 5
// 121.145 us; speedup vs baseline: 2.0653x; 2.0653x over previous
//
#include <hip/hip_runtime.h>
#include <hip/hip_bf16.h>

// B=2, S=2048, D=512, K_routes=64, H=8 (heads irrelevant: k-weighted sum is head-uniform)
#define S_DIM 2048
#define D_DIM 512
#define B_DIM 2
#define K_RT  64
#define M_DIM 4096   // B*S

typedef __attribute__((ext_vector_type(8))) short short8;   // 8 bf16 = 4 VGPRs (MFMA A/B frag)
typedef __attribute__((ext_vector_type(4))) float f32x4;    // MFMA C/D frag
typedef unsigned int u32;
#define AS1 __attribute__((address_space(1)))
#define AS3 __attribute__((address_space(3)))

static __device__ __forceinline__ float bf16lo_to_f(unsigned u) {
    union { unsigned u; float f; } c; c.u = u << 16; return c.f;
}
static __device__ __forceinline__ float bf16hi_to_f(unsigned u) {
    union { unsigned u; float f; } c; c.u = u & 0xffff0000u; return c.f;
}
static __device__ __forceinline__ unsigned short f_to_bf16(float f) {
    union { float f; unsigned u; } c; c.f = f;
    unsigned u = c.u;
    u += 0x7fffu + ((u >> 16) & 1u);   // RTNE (inputs finite/normal)
    return (unsigned short)(u >> 16);
}
static __device__ __forceinline__ unsigned pk2(float a, float b) {
    return (unsigned)f_to_bf16(a) | ((unsigned)f_to_bf16(b) << 16);
}

// ---------------------------------------------------------------------------
// prep: blocks [0,512) -> softmax weights w[s,k] (one wave per s, 4 per block);
//       blocks [512,3072) -> cast x / W_in / W_out to bf16 (float4 -> ushort4).
__global__ __launch_bounds__(256) void prep(
    const float* __restrict__ x, const int* __restrict__ routes,
    const float* __restrict__ distances,
    const float* __restrict__ Wi, const float* __restrict__ Wo,
    unsigned short* __restrict__ xb, unsigned short* __restrict__ wib,
    unsigned short* __restrict__ wob, float* __restrict__ w)
{
    const int blk = blockIdx.x;
    if (blk < 512) {
        const int lane = threadIdx.x & 63;
        const int wv   = threadIdx.x >> 6;
        const int s    = blk * 4 + wv;
        const int rt   = routes[s * K_RT + lane];
        const float v  = -distances[(size_t)s * S_DIM + rt];
        float mx = v;
        #pragma unroll
        for (int off = 32; off >= 1; off >>= 1) mx = fmaxf(mx, __shfl_xor(mx, off, 64));
        const float e = __expf(v - mx);
        float sum = e;
        #pragma unroll
        for (int off = 32; off >= 1; off >>= 1) sum += __shfl_xor(sum, off, 64);
        w[s * K_RT + lane] = e / sum;
    } else {
        const int g = (blk - 512) * 256 + threadIdx.x;   // one per float4
        const int NX = M_DIM * D_DIM / 4;                // 524288
        const int NW = D_DIM * D_DIM / 4;                // 65536
        const float* src; unsigned short* dst; int off;
        if (g < NX)           { src = x;  dst = xb;  off = g; }
        else if (g < NX + NW) { src = Wi; dst = wib; off = g - NX; }
        else                  { src = Wo; dst = wob; off = g - NX - NW; }
        const float4 v = ((const float4*)src)[off];
        ushort4 o;
        o.x = f_to_bf16(v.x); o.y = f_to_bf16(v.y);
        o.z = f_to_bf16(v.z); o.w = f_to_bf16(v.w);
        ((ushort4*)dst)[off] = o;
    }
}

// ---------------------------------------------------------------------------
// C = A * B^T, pure bf16 operands, m97-style global_load_lds staging.
// 64x64 tile, BK=32 (unpadded 64-B LDS rows: required by the DMA's
// wave-uniform-base + lane*16 layout; b128 frag reads take a benign 2x alias).
// Per K-iter per wave: 1 DMA(A) + 1 DMA(B) + 8 ds_read_b128 + 4 MFMA.
#define GBM 64
#define GBN 64
#define GBK 32

template<bool OUTF32>
__global__ __launch_bounds__(256) void gemm_bt(
    const unsigned short* __restrict__ A,   // M x K bf16
    const unsigned short* __restrict__ B,   // N x K bf16
    void* __restrict__ Cv,
    const float* __restrict__ bias, const float* __restrict__ residual,
    int M, int N, int K)
{
    __shared__ unsigned short As[GBM * GBK];   // 4 KB
    __shared__ unsigned short Bs[GBN * GBK];   // 4 KB

    const int tid  = threadIdx.x;
    const int lane = tid & 63;
    const int wv   = tid >> 6;
    const int wm   = (wv & 1) * 32;
    const int wn   = (wv >> 1) * 32;
    const int m0   = blockIdx.y * GBM;
    const int n0   = blockIdx.x * GBN;

    // DMA staging: wave wv covers rows [wv*16, wv*16+16); lane l sources
    // row wv*16 + l/4, k-elems (l&3)*8 .. +8 -> lands at LDS base + l*16 B.
    const int srow  = wv * 16 + (lane >> 2);
    const int skoff = (lane & 3) * 8;

    const int mi = lane & 15;
    const int kg = lane >> 4;

    f32x4 acc[2][2] = {};

    for (int k0 = 0; k0 < K; k0 += GBK) {
        __builtin_amdgcn_global_load_lds(
            (const AS1 u32*)(A + (size_t)(m0 + srow) * K + k0 + skoff),
            (AS3 u32*)(As + wv * 16 * GBK), 16, 0, 0);
        __builtin_amdgcn_global_load_lds(
            (const AS1 u32*)(B + (size_t)(n0 + srow) * K + k0 + skoff),
            (AS3 u32*)(Bs + wv * 16 * GBK), 16, 0, 0);
        __syncthreads();   // vmcnt(0) drain before frag reads

        short8 af0 = *(const short8*)(As + (wm +      mi) * GBK + kg * 8);
        short8 af1 = *(const short8*)(As + (wm + 16 + mi) * GBK + kg * 8);
        short8 bf0 = *(const short8*)(Bs + (wn +      mi) * GBK + kg * 8);
        short8 bf1 = *(const short8*)(Bs + (wn + 16 + mi) * GBK + kg * 8);

        acc[0][0] = __builtin_amdgcn_mfma_f32_16x16x32_bf16(af0, bf0, acc[0][0], 0, 0, 0);
        acc[0][1] = __builtin_amdgcn_mfma_f32_16x16x32_bf16(af0, bf1, acc[0][1], 0, 0, 0);
        acc[1][0] = __builtin_amdgcn_mfma_f32_16x16x32_bf16(af1, bf0, acc[1][0], 0, 0, 0);
        acc[1][1] = __builtin_amdgcn_mfma_f32_16x16x32_bf16(af1, bf1, acc[1][1], 0, 0, 0);
        __syncthreads();
    }

    // C/D layout: col = lane&15, row = (lane>>4)*4 + reg   [verified m89/m91]
    const int rb  = (lane >> 4) * 4;
    const int col = lane & 15;
    #pragma unroll
    for (int i = 0; i < 2; ++i) {
        #pragma unroll
        for (int j = 0; j < 2; ++j) {
            #pragma unroll
            for (int r = 0; r < 4; ++r) {
                const int m = m0 + wm + i * 16 + rb + r;
                const int n = n0 + wn + j * 16 + col;
                const float v = acc[i][j][r];
                if (OUTF32) {
                    ((float*)Cv)[(size_t)m * N + n] = v + bias[n] + residual[(size_t)m * N + n];
                } else {
                    ((unsigned short*)Cv)[(size_t)m * N + n] = f_to_bf16(v);
                }
            }
        }
    }
}

// ---------------------------------------------------------------------------
// fused[b,s,:] = sum_k w[s,k] * h[b,routes[s,k],:]   (w precomputed fp32)
// One wave per (b,s): lane k holds route_k/w_k; k-loop broadcasts via __shfl,
// 64 lanes read one 1 KB bf16 row coalesced (16 B/lane).
__global__ __launch_bounds__(256) void fuse_gather(
    const unsigned short* __restrict__ h, const int* __restrict__ routes,
    const float* __restrict__ w, unsigned short* __restrict__ fused)
{
    const int tid  = threadIdx.x;
    const int lane = tid & 63;
    const int wv   = tid >> 6;
    const int s    = blockIdx.x * 4 + wv;
    const int b    = blockIdx.y;

    const int   rt = routes[s * K_RT + lane];
    const float wl = w[s * K_RT + lane];

    const unsigned short* hb = h + (size_t)b * S_DIM * D_DIM;
    float acc[8] = {};
    #pragma unroll 8
    for (int k = 0; k < 64; ++k) {
        const int   rk = __shfl(rt, k, 64);
        const float wk = __shfl(wl, k, 64);
        const uint4 p = *(const uint4*)(hb + (size_t)rk * D_DIM + lane * 8);
        acc[0] = fmaf(wk, bf16lo_to_f(p.x), acc[0]);
        acc[1] = fmaf(wk, bf16hi_to_f(p.x), acc[1]);
        acc[2] = fmaf(wk, bf16lo_to_f(p.y), acc[2]);
        acc[3] = fmaf(wk, bf16hi_to_f(p.y), acc[3]);
        acc[4] = fmaf(wk, bf16lo_to_f(p.z), acc[4]);
        acc[5] = fmaf(wk, bf16hi_to_f(p.z), acc[5]);
        acc[6] = fmaf(wk, bf16lo_to_f(p.w), acc[6]);
        acc[7] = fmaf(wk, bf16hi_to_f(p.w), acc[7]);
    }
    uint4 o;
    o.x = pk2(acc[0], acc[1]);
    o.y = pk2(acc[2], acc[3]);
    o.z = pk2(acc[4], acc[5]);
    o.w = pk2(acc[6], acc[7]);
    *(uint4*)(fused + ((size_t)b * S_DIM + s) * D_DIM + lane * 8) = o;
}

// ---------------------------------------------------------------------------
extern "C" void kernel_launch(void* const* d_in, const int* in_sizes, int n_in,
                              void* d_out, int out_size, void* d_ws, size_t ws_size,
                              hipStream_t stream) {
    const float* x         = (const float*)d_in[0];
    const int*   routes    = (const int*)  d_in[1];
    const float* distances = (const float*)d_in[2];
    const float* W_in      = (const float*)d_in[3];
    const float* W_out     = (const float*)d_in[4];
    const float* b_out     = (const float*)d_in[5];
    float* out = (float*)d_out;

    // ws layout (bf16 elems): xb 2M | wib 256K | wob 256K | h 2M | fb 2M, then w fp32 128K
    unsigned short* xb  = (unsigned short*)d_ws;
    unsigned short* wib = xb  + (size_t)M_DIM * D_DIM;
    unsigned short* wob = wib + (size_t)D_DIM * D_DIM;
    unsigned short* hb  = wob + (size_t)D_DIM * D_DIM;
    unsigned short* fb  = hb  + (size_t)M_DIM * D_DIM;
    float*          w   = (float*)(fb + (size_t)M_DIM * D_DIM);

    const dim3 ggrid(D_DIM / GBN, M_DIM / GBM);   // 8 x 64 = 512 blocks

    // 1. softmax weights + bf16 casts (512 softmax blocks + 2560 cast blocks)
    prep<<<3072, 256, 0, stream>>>(x, routes, distances, W_in, W_out, xb, wib, wob, w);
    // 2. h = x @ W_in^T  (bf16 out)
    gemm_bt<false><<<ggrid, 256, 0, stream>>>(xb, wib, hb, nullptr, nullptr, M_DIM, D_DIM, D_DIM);
    // 3. gather + weighted sum (bf16 out)
    fuse_gather<<<dim3(S_DIM / 4, B_DIM), 256, 0, stream>>>(hb, routes, w, fb);
    // 4. out = fused @ W_out^T + b_out + x  (fp32 out + residual)
    gemm_bt<true><<<ggrid, 256, 0, stream>>>(fb, wob, out, b_out, x, M_DIM, D_DIM, D_DIM);
}

// Round 6
// 111.890 us; speedup vs baseline: 2.2361x; 1.0827x over previous
//
#include <hip/hip_runtime.h>
#include <hip/hip_bf16.h>

// B=2, S=2048, D=512, K_routes=64, H=8 (heads irrelevant: k-weighted sum is head-uniform)
#define S_DIM 2048
#define D_DIM 512
#define B_DIM 2
#define K_RT  64
#define M_DIM 4096   // B*S

typedef __attribute__((ext_vector_type(8))) short short8;   // 8 bf16 = 4 VGPRs (MFMA A/B frag)
typedef __attribute__((ext_vector_type(4))) float f32x4;    // MFMA C/D frag
typedef unsigned int u32;
#define AS1 __attribute__((address_space(1)))
#define AS3 __attribute__((address_space(3)))

static __device__ __forceinline__ float bf16lo_to_f(unsigned u) {
    union { unsigned u; float f; } c; c.u = u << 16; return c.f;
}
static __device__ __forceinline__ float bf16hi_to_f(unsigned u) {
    union { unsigned u; float f; } c; c.u = u & 0xffff0000u; return c.f;
}
static __device__ __forceinline__ unsigned short f_to_bf16(float f) {
    union { float f; unsigned u; } c; c.f = f;
    unsigned u = c.u;
    u += 0x7fffu + ((u >> 16) & 1u);   // RTNE (inputs finite/normal)
    return (unsigned short)(u >> 16);
}
static __device__ __forceinline__ unsigned pk2(float a, float b) {
    return (unsigned)f_to_bf16(a) | ((unsigned)f_to_bf16(b) << 16);
}

// ---------------------------------------------------------------------------
// prep: blocks [0,512) -> softmax weights w[s,k] (one wave per s, 4 per block);
//       blocks [512,3072) -> cast x / W_in / W_out to bf16 (float4 -> ushort4).
__global__ __launch_bounds__(256) void prep(
    const float* __restrict__ x, const int* __restrict__ routes,
    const float* __restrict__ distances,
    const float* __restrict__ Wi, const float* __restrict__ Wo,
    unsigned short* __restrict__ xb, unsigned short* __restrict__ wib,
    unsigned short* __restrict__ wob, float* __restrict__ w)
{
    const int blk = blockIdx.x;
    if (blk < 512) {
        const int lane = threadIdx.x & 63;
        const int wv   = threadIdx.x >> 6;
        const int s    = blk * 4 + wv;
        const int rt   = routes[s * K_RT + lane];
        const float v  = -distances[(size_t)s * S_DIM + rt];
        float mx = v;
        #pragma unroll
        for (int off = 32; off >= 1; off >>= 1) mx = fmaxf(mx, __shfl_xor(mx, off, 64));
        const float e = __expf(v - mx);
        float sum = e;
        #pragma unroll
        for (int off = 32; off >= 1; off >>= 1) sum += __shfl_xor(sum, off, 64);
        w[s * K_RT + lane] = e / sum;
    } else {
        const int g = (blk - 512) * 256 + threadIdx.x;   // one per float4
        const int NX = M_DIM * D_DIM / 4;                // 524288
        const int NW = D_DIM * D_DIM / 4;                // 65536
        const float* src; unsigned short* dst; int off;
        if (g < NX)           { src = x;  dst = xb;  off = g; }
        else if (g < NX + NW) { src = Wi; dst = wib; off = g - NX; }
        else                  { src = Wo; dst = wob; off = g - NX - NW; }
        const float4 v = ((const float4*)src)[off];
        ushort4 o;
        o.x = f_to_bf16(v.x); o.y = f_to_bf16(v.y);
        o.z = f_to_bf16(v.z); o.w = f_to_bf16(v.w);
        ((ushort4*)dst)[off] = o;
    }
}

// ---------------------------------------------------------------------------
// C = A * B^T, pure bf16 operands, m97-style global_load_lds staging.
// 64x64 tile, BK=32 (unpadded 64-B LDS rows: required by the DMA's
// wave-uniform-base + lane*16 layout; b128 frag reads take a benign 2x alias).
// Per K-iter per wave: 1 DMA(A) + 1 DMA(B) + 8 ds_read_b128 + 4 MFMA.
#define GBM 64
#define GBN 64
#define GBK 32

template<bool OUTF32>
__global__ __launch_bounds__(256) void gemm_bt(
    const unsigned short* __restrict__ A,   // M x K bf16
    const unsigned short* __restrict__ B,   // N x K bf16
    void* __restrict__ Cv,
    const float* __restrict__ bias, const float* __restrict__ residual,
    int M, int N, int K)
{
    __shared__ unsigned short As[GBM * GBK];   // 4 KB
    __shared__ unsigned short Bs[GBN * GBK];   // 4 KB

    const int tid  = threadIdx.x;
    const int lane = tid & 63;
    const int wv   = tid >> 6;
    const int wm   = (wv & 1) * 32;
    const int wn   = (wv >> 1) * 32;
    const int m0   = blockIdx.y * GBM;
    const int n0   = blockIdx.x * GBN;

    // DMA staging: wave wv covers rows [wv*16, wv*16+16); lane l sources
    // row wv*16 + l/4, k-elems (l&3)*8 .. +8 -> lands at LDS base + l*16 B.
    const int srow  = wv * 16 + (lane >> 2);
    const int skoff = (lane & 3) * 8;

    const int mi = lane & 15;
    const int kg = lane >> 4;

    f32x4 acc[2][2] = {};

    for (int k0 = 0; k0 < K; k0 += GBK) {
        __builtin_amdgcn_global_load_lds(
            (const AS1 u32*)(A + (size_t)(m0 + srow) * K + k0 + skoff),
            (AS3 u32*)(As + wv * 16 * GBK), 16, 0, 0);
        __builtin_amdgcn_global_load_lds(
            (const AS1 u32*)(B + (size_t)(n0 + srow) * K + k0 + skoff),
            (AS3 u32*)(Bs + wv * 16 * GBK), 16, 0, 0);
        __syncthreads();   // vmcnt(0) drain before frag reads

        short8 af0 = *(const short8*)(As + (wm +      mi) * GBK + kg * 8);
        short8 af1 = *(const short8*)(As + (wm + 16 + mi) * GBK + kg * 8);
        short8 bf0 = *(const short8*)(Bs + (wn +      mi) * GBK + kg * 8);
        short8 bf1 = *(const short8*)(Bs + (wn + 16 + mi) * GBK + kg * 8);

        acc[0][0] = __builtin_amdgcn_mfma_f32_16x16x32_bf16(af0, bf0, acc[0][0], 0, 0, 0);
        acc[0][1] = __builtin_amdgcn_mfma_f32_16x16x32_bf16(af0, bf1, acc[0][1], 0, 0, 0);
        acc[1][0] = __builtin_amdgcn_mfma_f32_16x16x32_bf16(af1, bf0, acc[1][0], 0, 0, 0);
        acc[1][1] = __builtin_amdgcn_mfma_f32_16x16x32_bf16(af1, bf1, acc[1][1], 0, 0, 0);
        __syncthreads();
    }

    // C/D layout: col = lane&15, row = (lane>>4)*4 + reg   [verified m89/m91]
    const int rb  = (lane >> 4) * 4;
    const int col = lane & 15;
    #pragma unroll
    for (int i = 0; i < 2; ++i) {
        #pragma unroll
        for (int j = 0; j < 2; ++j) {
            #pragma unroll
            for (int r = 0; r < 4; ++r) {
                const int m = m0 + wm + i * 16 + rb + r;
                const int n = n0 + wn + j * 16 + col;
                const float v = acc[i][j][r];
                if (OUTF32) {
                    ((float*)Cv)[(size_t)m * N + n] = v + bias[n] + residual[(size_t)m * N + n];
                } else {
                    ((unsigned short*)Cv)[(size_t)m * N + n] = f_to_bf16(v);
                }
            }
        }
    }
}

// ---------------------------------------------------------------------------
// fused[b,s,:] = sum_k w[s,k] * h[b,routes[s,k],:]   (w precomputed fp32)
// One wave per (b,s). Full unroll over k: route/weight come via v_readlane
// into SGPRs -> scalar row base (SALU), loop-invariant vector offset lane*16B,
// v_fmac with SGPR weight. b = blockIdx.x & 1 aligns b with XCD parity so each
// XCD's 4 MiB L2 holds mostly one b's 4 MB h-slice.
__global__ __launch_bounds__(256) void fuse_gather(
    const unsigned short* __restrict__ h, const int* __restrict__ routes,
    const float* __restrict__ w, unsigned short* __restrict__ fused)
{
    const int tid  = threadIdx.x;
    const int lane = tid & 63;
    const int wv   = tid >> 6;
    const int bx   = blockIdx.x;        // 0..1023
    const int b    = bx & 1;
    const int s    = (bx >> 1) * 4 + wv;

    const int   rt = routes[s * K_RT + lane];
    const float wl = w[s * K_RT + lane];

    const unsigned short* hb = h + (size_t)b * S_DIM * D_DIM;
    float acc[8] = {};
    #pragma unroll
    for (int k = 0; k < 64; ++k) {
        const int   rk = __builtin_amdgcn_readlane(rt, k);
        const float wk = __int_as_float(__builtin_amdgcn_readlane(__float_as_int(wl), k));
        const uint4 p = *(const uint4*)(hb + (size_t)rk * D_DIM + lane * 8);
        acc[0] = fmaf(wk, bf16lo_to_f(p.x), acc[0]);
        acc[1] = fmaf(wk, bf16hi_to_f(p.x), acc[1]);
        acc[2] = fmaf(wk, bf16lo_to_f(p.y), acc[2]);
        acc[3] = fmaf(wk, bf16hi_to_f(p.y), acc[3]);
        acc[4] = fmaf(wk, bf16lo_to_f(p.z), acc[4]);
        acc[5] = fmaf(wk, bf16hi_to_f(p.z), acc[5]);
        acc[6] = fmaf(wk, bf16lo_to_f(p.w), acc[6]);
        acc[7] = fmaf(wk, bf16hi_to_f(p.w), acc[7]);
    }
    uint4 o;
    o.x = pk2(acc[0], acc[1]);
    o.y = pk2(acc[2], acc[3]);
    o.z = pk2(acc[4], acc[5]);
    o.w = pk2(acc[6], acc[7]);
    *(uint4*)(fused + ((size_t)b * S_DIM + s) * D_DIM + lane * 8) = o;
}

// ---------------------------------------------------------------------------
extern "C" void kernel_launch(void* const* d_in, const int* in_sizes, int n_in,
                              void* d_out, int out_size, void* d_ws, size_t ws_size,
                              hipStream_t stream) {
    const float* x         = (const float*)d_in[0];
    const int*   routes    = (const int*)  d_in[1];
    const float* distances = (const float*)d_in[2];
    const float* W_in      = (const float*)d_in[3];
    const float* W_out     = (const float*)d_in[4];
    const float* b_out     = (const float*)d_in[5];
    float* out = (float*)d_out;

    // ws layout (bf16 elems): xb 2M | wib 256K | wob 256K | h 2M | fb 2M, then w fp32 128K
    unsigned short* xb  = (unsigned short*)d_ws;
    unsigned short* wib = xb  + (size_t)M_DIM * D_DIM;
    unsigned short* wob = wib + (size_t)D_DIM * D_DIM;
    unsigned short* hb  = wob + (size_t)D_DIM * D_DIM;
    unsigned short* fb  = hb  + (size_t)M_DIM * D_DIM;
    float*          w   = (float*)(fb + (size_t)M_DIM * D_DIM);

    const dim3 ggrid(D_DIM / GBN, M_DIM / GBM);   // 8 x 64 = 512 blocks

    // 1. softmax weights + bf16 casts (512 softmax blocks + 2560 cast blocks)
    prep<<<3072, 256, 0, stream>>>(x, routes, distances, W_in, W_out, xb, wib, wob, w);
    // 2. h = x @ W_in^T  (bf16 out)
    gemm_bt<false><<<ggrid, 256, 0, stream>>>(xb, wib, hb, nullptr, nullptr, M_DIM, D_DIM, D_DIM);
    // 3. gather + weighted sum (bf16 out), XCD-parity b swizzle
    fuse_gather<<<dim3(1024), 256, 0, stream>>>(hb, routes, w, fb);
    // 4. out = fused @ W_out^T + b_out + x  (fp32 out + residual)
    gemm_bt<true><<<ggrid, 256, 0, stream>>>(fb, wob, out, b_out, x, M_DIM, D_DIM, D_DIM);
}

// Round 7
// 111.594 us; speedup vs baseline: 2.2420x; 1.0026x over previous
//
#include <hip/hip_runtime.h>
#include <hip/hip_bf16.h>

// B=2, S=2048, D=512, K_routes=64, H=8 (heads irrelevant: k-weighted sum is head-uniform)
#define S_DIM 2048
#define D_DIM 512
#define B_DIM 2
#define K_RT  64
#define M_DIM 4096   // B*S

typedef __attribute__((ext_vector_type(8))) short short8;   // 8 bf16 = 4 VGPRs (MFMA A/B frag)
typedef __attribute__((ext_vector_type(4))) float f32x4;    // MFMA C/D frag
typedef unsigned int u32;
#define AS1 __attribute__((address_space(1)))
#define AS3 __attribute__((address_space(3)))

static __device__ __forceinline__ float bf16lo_to_f(unsigned u) {
    union { unsigned u; float f; } c; c.u = u << 16; return c.f;
}
static __device__ __forceinline__ float bf16hi_to_f(unsigned u) {
    union { unsigned u; float f; } c; c.u = u & 0xffff0000u; return c.f;
}
static __device__ __forceinline__ unsigned short f_to_bf16(float f) {
    union { float f; unsigned u; } c; c.f = f;
    unsigned u = c.u;
    u += 0x7fffu + ((u >> 16) & 1u);   // RTNE (inputs finite/normal)
    return (unsigned short)(u >> 16);
}
static __device__ __forceinline__ unsigned pk2(float a, float b) {
    return (unsigned)f_to_bf16(a) | ((unsigned)f_to_bf16(b) << 16);
}

// ---------------------------------------------------------------------------
// prep: pure streaming cast x / W_in / W_out fp32 -> bf16 (float4 -> ushort4).
// Exact grid: (524288 + 2*65536) float4s / 256 = 2560 blocks.
__global__ __launch_bounds__(256) void prep_cast(
    const float* __restrict__ x, const float* __restrict__ Wi, const float* __restrict__ Wo,
    unsigned short* __restrict__ xb, unsigned short* __restrict__ wib,
    unsigned short* __restrict__ wob)
{
    const int g = blockIdx.x * 256 + threadIdx.x;    // one per float4
    const int NX = M_DIM * D_DIM / 4;                // 524288
    const int NW = D_DIM * D_DIM / 4;                // 65536
    const float* src; unsigned short* dst; int off;
    if (g < NX)           { src = x;  dst = xb;  off = g; }
    else if (g < NX + NW) { src = Wi; dst = wib; off = g - NX; }
    else                  { src = Wo; dst = wob; off = g - NX - NW; }
    const float4 v = ((const float4*)src)[off];
    ushort4 o;
    o.x = f_to_bf16(v.x); o.y = f_to_bf16(v.y);
    o.z = f_to_bf16(v.z); o.w = f_to_bf16(v.w);
    ((ushort4*)dst)[off] = o;
}

// ---------------------------------------------------------------------------
// C = A * B^T, pure bf16 operands, global_load_lds staging.
// 64x64 tile, BK=64 stored as two 32-k LDS panels (each panel keeps the
// DMA-required wave-uniform-base + lane*16B layout with 64-B rows).
// 8 K-iters: per iter per wave 4 DMA + 8 ds_read_b128 + 8 MFMA, 2 barriers.
#define GBM 64
#define GBN 64
#define GBK 64

template<bool OUTF32>
__global__ __launch_bounds__(256) void gemm_bt(
    const unsigned short* __restrict__ A,   // M x K bf16
    const unsigned short* __restrict__ B,   // N x K bf16
    void* __restrict__ Cv,
    const float* __restrict__ bias, const float* __restrict__ residual,
    int M, int N, int K)
{
    __shared__ unsigned short As[2][GBM * 32];   // 2 panels x 4 KB
    __shared__ unsigned short Bs[2][GBN * 32];

    const int tid  = threadIdx.x;
    const int lane = tid & 63;
    const int wv   = tid >> 6;
    const int wm   = (wv & 1) * 32;
    const int wn   = (wv >> 1) * 32;
    const int m0   = blockIdx.y * GBM;
    const int n0   = blockIdx.x * GBN;

    // DMA staging: wave wv covers rows [wv*16, wv*16+16); per panel, lane l
    // sources row wv*16 + l/4, k-elems (l&3)*8..+8 -> LDS base + l*16 B.
    const int srow  = wv * 16 + (lane >> 2);
    const int skoff = (lane & 3) * 8;

    const int mi = lane & 15;
    const int kg = lane >> 4;

    f32x4 acc[2][2] = {};

    for (int k0 = 0; k0 < K; k0 += GBK) {
        const size_t arow = (size_t)(m0 + srow) * K + k0 + skoff;
        const size_t brow = (size_t)(n0 + srow) * K + k0 + skoff;
        __builtin_amdgcn_global_load_lds((const AS1 u32*)(A + arow),
                                         (AS3 u32*)(As[0] + wv * 512), 16, 0, 0);
        __builtin_amdgcn_global_load_lds((const AS1 u32*)(A + arow + 32),
                                         (AS3 u32*)(As[1] + wv * 512), 16, 0, 0);
        __builtin_amdgcn_global_load_lds((const AS1 u32*)(B + brow),
                                         (AS3 u32*)(Bs[0] + wv * 512), 16, 0, 0);
        __builtin_amdgcn_global_load_lds((const AS1 u32*)(B + brow + 32),
                                         (AS3 u32*)(Bs[1] + wv * 512), 16, 0, 0);
        __syncthreads();   // vmcnt(0) drain before frag reads

        #pragma unroll
        for (int kh = 0; kh < 2; ++kh) {
            short8 af0 = *(const short8*)(As[kh] + (wm +      mi) * 32 + kg * 8);
            short8 af1 = *(const short8*)(As[kh] + (wm + 16 + mi) * 32 + kg * 8);
            short8 bf0 = *(const short8*)(Bs[kh] + (wn +      mi) * 32 + kg * 8);
            short8 bf1 = *(const short8*)(Bs[kh] + (wn + 16 + mi) * 32 + kg * 8);

            acc[0][0] = __builtin_amdgcn_mfma_f32_16x16x32_bf16(af0, bf0, acc[0][0], 0, 0, 0);
            acc[0][1] = __builtin_amdgcn_mfma_f32_16x16x32_bf16(af0, bf1, acc[0][1], 0, 0, 0);
            acc[1][0] = __builtin_amdgcn_mfma_f32_16x16x32_bf16(af1, bf0, acc[1][0], 0, 0, 0);
            acc[1][1] = __builtin_amdgcn_mfma_f32_16x16x32_bf16(af1, bf1, acc[1][1], 0, 0, 0);
        }
        __syncthreads();
    }

    // C/D layout: col = lane&15, row = (lane>>4)*4 + reg   [verified m89/m91]
    const int rb  = (lane >> 4) * 4;
    const int col = lane & 15;
    #pragma unroll
    for (int i = 0; i < 2; ++i) {
        #pragma unroll
        for (int j = 0; j < 2; ++j) {
            #pragma unroll
            for (int r = 0; r < 4; ++r) {
                const int m = m0 + wm + i * 16 + rb + r;
                const int n = n0 + wn + j * 16 + col;
                const float v = acc[i][j][r];
                if (OUTF32) {
                    ((float*)Cv)[(size_t)m * N + n] = v + bias[n] + residual[(size_t)m * N + n];
                } else {
                    ((unsigned short*)Cv)[(size_t)m * N + n] = f_to_bf16(v);
                }
            }
        }
    }
}

// ---------------------------------------------------------------------------
// fused[b,s,:] = sum_k softmax_k(-dist[s,routes[s,k]]) * h[b,routes[s,k],:]
// One wave per (b,s): lane k owns route_k; in-wave shfl softmax; then full
// unroll over k with v_readlane -> SGPR route/weight (scalar row base, SALU),
// loop-invariant vector offset lane*16B. b = bx&1 aligns b with XCD parity so
// each XCD's 4 MiB L2 holds mostly one b's 4 MB h-slice.
__global__ __launch_bounds__(256) void fuse_gather(
    const unsigned short* __restrict__ h, const int* __restrict__ routes,
    const float* __restrict__ distances, unsigned short* __restrict__ fused)
{
    const int tid  = threadIdx.x;
    const int lane = tid & 63;
    const int wv   = tid >> 6;
    const int bx   = blockIdx.x;        // 0..1023
    const int b    = bx & 1;
    const int s    = (bx >> 1) * 4 + wv;

    const int rt = routes[s * K_RT + lane];
    const float v = -distances[(size_t)s * S_DIM + rt];
    float mx = v;
    #pragma unroll
    for (int off = 32; off >= 1; off >>= 1) mx = fmaxf(mx, __shfl_xor(mx, off, 64));
    const float e = __expf(v - mx);
    float sum = e;
    #pragma unroll
    for (int off = 32; off >= 1; off >>= 1) sum += __shfl_xor(sum, off, 64);
    const float wl = e / sum;

    const unsigned short* hb = h + (size_t)b * S_DIM * D_DIM;
    float acc[8] = {};
    #pragma unroll
    for (int k = 0; k < 64; ++k) {
        const int   rk = __builtin_amdgcn_readlane(rt, k);
        const float wk = __int_as_float(__builtin_amdgcn_readlane(__float_as_int(wl), k));
        const uint4 p = *(const uint4*)(hb + (size_t)rk * D_DIM + lane * 8);
        acc[0] = fmaf(wk, bf16lo_to_f(p.x), acc[0]);
        acc[1] = fmaf(wk, bf16hi_to_f(p.x), acc[1]);
        acc[2] = fmaf(wk, bf16lo_to_f(p.y), acc[2]);
        acc[3] = fmaf(wk, bf16hi_to_f(p.y), acc[3]);
        acc[4] = fmaf(wk, bf16lo_to_f(p.z), acc[4]);
        acc[5] = fmaf(wk, bf16hi_to_f(p.z), acc[5]);
        acc[6] = fmaf(wk, bf16lo_to_f(p.w), acc[6]);
        acc[7] = fmaf(wk, bf16hi_to_f(p.w), acc[7]);
    }
    uint4 o;
    o.x = pk2(acc[0], acc[1]);
    o.y = pk2(acc[2], acc[3]);
    o.z = pk2(acc[4], acc[5]);
    o.w = pk2(acc[6], acc[7]);
    *(uint4*)(fused + ((size_t)b * S_DIM + s) * D_DIM + lane * 8) = o;
}

// ---------------------------------------------------------------------------
extern "C" void kernel_launch(void* const* d_in, const int* in_sizes, int n_in,
                              void* d_out, int out_size, void* d_ws, size_t ws_size,
                              hipStream_t stream) {
    const float* x         = (const float*)d_in[0];
    const int*   routes    = (const int*)  d_in[1];
    const float* distances = (const float*)d_in[2];
    const float* W_in      = (const float*)d_in[3];
    const float* W_out     = (const float*)d_in[4];
    const float* b_out     = (const float*)d_in[5];
    float* out = (float*)d_out;

    // ws layout (bf16 elems): xb 2M | wib 256K | wob 256K | h 2M | fb 2M = 13 MB
    unsigned short* xb  = (unsigned short*)d_ws;
    unsigned short* wib = xb  + (size_t)M_DIM * D_DIM;
    unsigned short* wob = wib + (size_t)D_DIM * D_DIM;
    unsigned short* hb  = wob + (size_t)D_DIM * D_DIM;
    unsigned short* fb  = hb  + (size_t)M_DIM * D_DIM;

    const dim3 ggrid(D_DIM / GBN, M_DIM / GBM);   // 8 x 64 = 512 blocks

    // 1. streaming bf16 casts (exact grid)
    prep_cast<<<2560, 256, 0, stream>>>(x, W_in, W_out, xb, wib, wob);
    // 2. h = x @ W_in^T  (bf16 out)
    gemm_bt<false><<<ggrid, 256, 0, stream>>>(xb, wib, hb, nullptr, nullptr, M_DIM, D_DIM, D_DIM);
    // 3. softmax + gather + weighted sum (bf16 out), XCD-parity b swizzle
    fuse_gather<<<dim3(1024), 256, 0, stream>>>(hb, routes, distances, fb);
    // 4. out = fused @ W_out^T + b_out + x  (fp32 out + residual)
    gemm_bt<true><<<ggrid, 256, 0, stream>>>(fb, wob, out, b_out, x, M_DIM, D_DIM, D_DIM);
}